// Round 4
// baseline (91.905 us; speedup 1.0000x reference)
//
#include <hip/hip_runtime.h>

#define B_DIM 256
#define E_DIM 8192
#define C_DIM 19
#define XBLK  32                 // E_DIM / B_DIM
#define NBLK  (XBLK * C_DIM)     // 608 pair blocks

// ws layout (floats):
//  [0   .. 607 ]  capP[c*32+x]  partial count of (e_true>=0.5)   (K1 -> K2, plain)
//  [608 .. 626 ]  n_pos[c]                                        (K1 -> K2, plain)
//  [627 .. 645 ]  sum_yp[c]                                       (K1 -> K2, plain)
//  [646 .. 1253]  mP[c*32+x]    partial weighted pair sum         (K2, release)
//  [1254]         done counter (uint32)                           (init 0 in K1)
#define WS_CAP  0
#define WS_NPOS 608
#define WS_SYP  627
#define WS_M    646
#define WS_CNT  1254

__device__ __forceinline__ float agent_load_acq(const float* p) {
    return __hip_atomic_load(p, __ATOMIC_ACQUIRE, __HIP_MEMORY_SCOPE_AGENT);
}
__device__ __forceinline__ void agent_store_rel(float* p, float v) {
    __hip_atomic_store(p, v, __ATOMIC_RELEASE, __HIP_MEMORY_SCOPE_AGENT);
}

// Block-wide sum (256 threads = 4 waves). Result valid on tid==0 only.
__device__ __forceinline__ float block_sum(float v, int tid, float* red4) {
    #pragma unroll
    for (int off = 32; off > 0; off >>= 1) v += __shfl_down(v, off, 64);
    if ((tid & 63) == 0) red4[tid >> 6] = v;
    __syncthreads();
    float r = 0.0f;
    if (tid == 0) r = red4[0] + red4[1] + red4[2] + red4[3];
    __syncthreads();
    return r;
}

// K1: grid (32,19) x 256. Cap partials; x==0 blocks also do the B-reductions
// and block (0,0) zeroes the done counter. Kernel boundary makes all of this
// visible to K2 (proven in R2: plain cross-kernel stores/loads, absmax 0).
__global__ void __launch_bounds__(B_DIM)
rocstar_k1(const float* __restrict__ y_pred,
           const float* __restrict__ y_true,
           const float* __restrict__ epoch_true,
           float* __restrict__ ws) {
    const int c   = blockIdx.y;
    const int x   = blockIdx.x;
    const int tid = threadIdx.x;
    const int j   = x * B_DIM + tid;
    __shared__ float red4[4];

    const float cnt = (epoch_true[j * C_DIM + c] >= 0.5f) ? 1.0f : 0.0f;
    const float cs  = block_sum(cnt, tid, red4);
    if (tid == 0) ws[WS_CAP + c * XBLK + x] = cs;

    if (x == 0) {
        const float ypv = y_pred[tid * C_DIM + c];
        const float ytv = (y_true[tid * C_DIM + c] >= 0.5f) ? 1.0f : 0.0f;
        const float np  = block_sum(ytv, tid, red4);
        if (tid == 0) ws[WS_NPOS + c] = np;
        const float sy  = block_sum(ypv, tid, red4);
        if (tid == 0) {
            ws[WS_SYP + c] = sy;
            if (c == 0) ((unsigned int*)ws)[WS_CNT] = 0u;  // init done counter
        }
    }
}

// K2: grid (32,19) x 256. Pair sums with p known upfront; the LAST block to
// finish (atomic ticket) folds all 608 partials and writes out[0]. No spins.
__global__ void __launch_bounds__(B_DIM)
rocstar_k2(const float* __restrict__ y_pred,
           const float* __restrict__ y_true,
           const float* __restrict__ epoch_pred,
           const float* __restrict__ epoch_true,
           const float* __restrict__ gamma,
           const float* __restrict__ rand_pos,
           const float* __restrict__ rand_neg,
           float* __restrict__ ws,
           float* __restrict__ out) {
    const int c   = blockIdx.y;
    const int x   = blockIdx.x;
    const int tid = threadIdx.x;
    const int j   = x * B_DIM + tid;

    __shared__ float4 s_yp4[B_DIM / 2];   // {yp_i, pm_i, yp_{i+1}, pm_{i+1}}
    __shared__ float  red4[4];
    __shared__ int    s_last;

    ((float2*)s_yp4)[tid] = make_float2(
        y_pred[tid * C_DIM + c],
        (y_true[tid * C_DIM + c] >= 0.5f) ? 1.0f : 0.0f);

    // cap from K1's partials (uniform-address, L2-hot)
    float cap = 0.0f;
    #pragma unroll
    for (int t = 0; t < XBLK; ++t) cap += ws[WS_CAP + c * XBLK + t];
    const float p = 1000.0f / fmaxf(cap, 1.0f);   // MAX_POS / cap_pos (f32, as ref)
    const float g = gamma[c];

    const float ep = epoch_pred[j * C_DIM + c];
    const bool  et = epoch_true[j * C_DIM + c] >= 0.5f;
    const float rp = rand_pos[j * C_DIM + c];
    const float rn = rand_neg[j * C_DIM + c];

    // faithful to the reference "bug": both masks use p from cap_pos
    const float w = ((et ? rp : rn) < p) ? 1.0f : 0.0f;

    // combined form:
    // et=0 (epoch neg, m2): d = (ep - yp) + g, mask = pm      -> s = +1
    // et=1 (epoch pos, m3): d = (yp - ep) + g, mask = 1 - pm  -> s = -1
    const float s    = et ? -1.0f : 1.0f;
    const float a    = fmaf(s, ep, g);
    const float ns   = -s;
    const float et01 = et ? 1.0f : 0.0f;

    __syncthreads();

    float acc0 = 0.0f, acc1 = 0.0f;
    if (__ballot(w != 0.0f)) {          // skip only if whole wave inactive
        #pragma unroll 8
        for (int k = 0; k < B_DIM / 2; ++k) {
            const float4 v = s_yp4[k];  // broadcast ds_read_b128, conflict-free
            float d0 = fmaxf(fmaf(ns, v.x, a), 0.0f);
            float m0 = fmaf(s, v.y, et01);       // pm or 1-pm
            acc0 = fmaf(d0 * d0, m0, acc0);
            float d1 = fmaxf(fmaf(ns, v.z, a), 0.0f);
            float m1 = fmaf(s, v.w, et01);
            acc1 = fmaf(d1 * d1, m1, acc1);
        }
    }

    const float bs = block_sum(w * (acc0 + acc1), tid, red4);
    if (tid == 0) {
        agent_store_rel(&ws[WS_M + c * XBLK + x], bs);
        unsigned int old = __hip_atomic_fetch_add(&((unsigned int*)ws)[WS_CNT], 1u,
                                                  __ATOMIC_ACQ_REL,
                                                  __HIP_MEMORY_SCOPE_AGENT);
        s_last = (old == NBLK - 1) ? 1 : 0;
    }
    __syncthreads();

    // last-finishing block folds everything (all partials visible via the
    // release-store -> acq_rel RMW chain on the counter)
    if (s_last && tid < 64) {
        float rv = 0.0f;
        if (tid < C_DIM) {
            float m = 0.0f;
            #pragma unroll
            for (int t = 0; t < XBLK; ++t)
                m += agent_load_acq(&ws[WS_M + tid * XBLK + t]);
            float v = m / 1000.0f;                // m2/MAX_POS + m3/MAX_NEG
            if (isnan(v)) v = 0.0f;
            const float np = ws[WS_NPOS + tid];
            rv = (np == 0.0f || np == (float)B_DIM)
                     ? ws[WS_SYP + tid] * 1e-8f   // degenerate: sum(yp)*1e-8
                     : v;
        }
        #pragma unroll
        for (int off = 16; off > 0; off >>= 1) rv += __shfl_down(rv, off, 64);
        if (tid == 0) out[0] = rv / (float)C_DIM; // mean over classes
    }
}

extern "C" void kernel_launch(void* const* d_in, const int* in_sizes, int n_in,
                              void* d_out, int out_size, void* d_ws, size_t ws_size,
                              hipStream_t stream) {
    const float* y_pred     = (const float*)d_in[0];
    const float* y_true     = (const float*)d_in[1];
    const float* epoch_pred = (const float*)d_in[2];
    const float* epoch_true = (const float*)d_in[3];
    const float* gamma      = (const float*)d_in[4];
    const float* rand_pos   = (const float*)d_in[5];
    const float* rand_neg   = (const float*)d_in[6];
    float*       out        = (float*)d_out;
    float*       ws         = (float*)d_ws;

    const dim3 grid(XBLK, C_DIM);   // 32 x 19
    rocstar_k1<<<grid, B_DIM, 0, stream>>>(y_pred, y_true, epoch_true, ws);
    rocstar_k2<<<grid, B_DIM, 0, stream>>>(y_pred, y_true, epoch_pred, epoch_true,
                                           gamma, rand_pos, rand_neg, ws, out);
}

// Round 5
// 78.153 us; speedup vs baseline: 1.1760x; 1.1760x over previous
//
#include <hip/hip_runtime.h>

#define B_DIM 256
#define E_DIM 8192
#define C_DIM 19
#define XBLK  32   // E_DIM / B_DIM

// ws layout (floats), all plain writes (no atomics, no pre-zero needed):
//  [0    .. 607 ]  capP[c*32+x]  partial count of (e_true>=0.5) over j-slice
//  [608  .. 626 ]  n_pos[c]      count of (y_true>=0.5) over B
//  [627  .. 645 ]  sum_yp[c]     sum of y_pred over B
//  [646  .. 1253]  mP[c*32+x]    partial weighted pair sum
#define WS_CAP  0
#define WS_NPOS 608
#define WS_SYP  627
#define WS_M    646

// Block-wide sum (256 threads = 4 waves). Result valid on tid==0 only.
__device__ __forceinline__ float block_sum(float v, int tid, float* red4) {
    #pragma unroll
    for (int off = 32; off > 0; off >>= 1) v += __shfl_down(v, off, 64);
    if ((tid & 63) == 0) red4[tid >> 6] = v;
    __syncthreads();
    float r = 0.0f;
    if (tid == 0) r = red4[0] + red4[1] + red4[2] + red4[3];
    __syncthreads();
    return r;
}

// K1: grid (32,19) x 256. Per-class partial cap counts; block x==0 also does
// the B-reductions (n_pos, sum_yp). Plain writes; kernel boundary publishes.
__global__ void __launch_bounds__(B_DIM)
rocstar_k1(const float* __restrict__ y_pred,
           const float* __restrict__ y_true,
           const float* __restrict__ epoch_true,
           float* __restrict__ ws) {
    const int c   = blockIdx.y;
    const int x   = blockIdx.x;
    const int tid = threadIdx.x;
    const int j   = x * B_DIM + tid;
    __shared__ float red4[4];

    const float cnt = (epoch_true[j * C_DIM + c] >= 0.5f) ? 1.0f : 0.0f;
    const float cs  = block_sum(cnt, tid, red4);
    if (tid == 0) ws[WS_CAP + c * XBLK + x] = cs;

    if (x == 0) {
        const float ypv = y_pred[tid * C_DIM + c];
        const float ytv = (y_true[tid * C_DIM + c] >= 0.5f) ? 1.0f : 0.0f;
        const float np  = block_sum(ytv, tid, red4);
        if (tid == 0) ws[WS_NPOS + c] = np;
        const float sy  = block_sum(ypv, tid, red4);
        if (tid == 0) ws[WS_SYP + c] = sy;
    }
}

// K2: grid (32,19) x 256. Pair sums, combined +/-s form (5 VALU ops/element):
// et=0 (epoch neg, m2): d = (ep - yp) + g, mask = pm      -> s = +1
// et=1 (epoch pos, m3): d = (yp - ep) + g, mask = 1 - pm  -> s = -1
__global__ void __launch_bounds__(B_DIM)
rocstar_k2(const float* __restrict__ y_pred,
           const float* __restrict__ y_true,
           const float* __restrict__ epoch_pred,
           const float* __restrict__ epoch_true,
           const float* __restrict__ gamma,
           const float* __restrict__ rand_pos,
           const float* __restrict__ rand_neg,
           float* __restrict__ ws) {
    const int c   = blockIdx.y;
    const int x   = blockIdx.x;
    const int tid = threadIdx.x;
    const int j   = x * B_DIM + tid;

    __shared__ float4 s_yp4[B_DIM / 2];   // {yp_i, pm_i, yp_{i+1}, pm_{i+1}}
    __shared__ float  red4[4];

    ((float2*)s_yp4)[tid] = make_float2(
        y_pred[tid * C_DIM + c],
        (y_true[tid * C_DIM + c] >= 0.5f) ? 1.0f : 0.0f);

    // cap from K1's partials (uniform-address scalar loads, L2-hot)
    float cap = 0.0f;
    #pragma unroll
    for (int t = 0; t < XBLK; ++t) cap += ws[WS_CAP + c * XBLK + t];
    const float p = 1000.0f / fmaxf(cap, 1.0f);   // MAX_POS / cap_pos (f32, as ref)
    const float g = gamma[c];

    const float ep = epoch_pred[j * C_DIM + c];
    const bool  et = epoch_true[j * C_DIM + c] >= 0.5f;
    const float rp = rand_pos[j * C_DIM + c];
    const float rn = rand_neg[j * C_DIM + c];

    // faithful to the reference "bug": both masks use p from cap_pos
    const float w    = ((et ? rp : rn) < p) ? 1.0f : 0.0f;
    const float s    = et ? -1.0f : 1.0f;
    const float a    = fmaf(s, ep, g);        // s*ep + g
    const float ns   = -s;
    const float et01 = et ? 1.0f : 0.0f;

    __syncthreads();

    float acc0 = 0.0f, acc1 = 0.0f;
    #pragma unroll 8
    for (int k = 0; k < B_DIM / 2; ++k) {
        const float4 v = s_yp4[k];            // broadcast ds_read_b128, conflict-free
        float d0 = fmaxf(fmaf(ns, v.x, a), 0.0f);
        float m0 = fmaf(s, v.y, et01);        // pm or 1-pm
        acc0 = fmaf(d0 * d0, m0, acc0);
        float d1 = fmaxf(fmaf(ns, v.z, a), 0.0f);
        float m1 = fmaf(s, v.w, et01);
        acc1 = fmaf(d1 * d1, m1, acc1);
    }

    const float bs = block_sum(w * (acc0 + acc1), tid, red4);
    if (tid == 0) ws[WS_M + c * XBLK + x] = bs;
}

// K3: one block. Thread c<19 folds its class's 32 partials + degenerate logic;
// single-wave shuffle reduce over classes.
__global__ void rocstar_k3(const float* __restrict__ ws,
                           float* __restrict__ out) {
    const int tid = threadIdx.x;
    float r = 0.0f;
    if (tid < C_DIM) {
        float m = 0.0f;
        #pragma unroll
        for (int t = 0; t < XBLK; ++t) m += ws[WS_M + tid * XBLK + t];
        float v = m / 1000.0f;                  // m2/MAX_POS + m3/MAX_NEG
        if (isnan(v)) v = 0.0f;
        const float npos = ws[WS_NPOS + tid];
        r = (npos == 0.0f || npos == (float)B_DIM)
                ? ws[WS_SYP + tid] * 1e-8f      // degenerate: sum(yp)*1e-8
                : v;
    }
    #pragma unroll
    for (int off = 16; off > 0; off >>= 1) r += __shfl_down(r, off, 64);
    if (tid == 0) out[0] = r / (float)C_DIM;    // mean over classes
}

extern "C" void kernel_launch(void* const* d_in, const int* in_sizes, int n_in,
                              void* d_out, int out_size, void* d_ws, size_t ws_size,
                              hipStream_t stream) {
    const float* y_pred     = (const float*)d_in[0];
    const float* y_true     = (const float*)d_in[1];
    const float* epoch_pred = (const float*)d_in[2];
    const float* epoch_true = (const float*)d_in[3];
    const float* gamma      = (const float*)d_in[4];
    const float* rand_pos   = (const float*)d_in[5];
    const float* rand_neg   = (const float*)d_in[6];
    float*       out        = (float*)d_out;
    float*       ws         = (float*)d_ws;

    const dim3 grid(XBLK, C_DIM);   // 32 x 19
    rocstar_k1<<<grid, B_DIM, 0, stream>>>(y_pred, y_true, epoch_true, ws);
    rocstar_k2<<<grid, B_DIM, 0, stream>>>(y_pred, y_true, epoch_pred, epoch_true,
                                           gamma, rand_pos, rand_neg, ws);
    rocstar_k3<<<1, 64, 0, stream>>>(ws, out);
}

// Round 6
// 75.334 us; speedup vs baseline: 1.2200x; 1.0374x over previous
//
#include <hip/hip_runtime.h>

#define B_DIM 256
#define E_DIM 8192
#define C_DIM 19
#define XBLK  32   // E_DIM / B_DIM

// ws layout (floats), all plain writes (no atomics, no pre-zero needed):
//  [0    .. 607 ]  capP[c*32+x]  partial count of (e_true>=0.5) over j-slice
//  [608  .. 626 ]  n_pos[c]      count of (y_true>=0.5) over B
//  [627  .. 645 ]  sum_yp[c]     sum of y_pred over B
//  [646  .. 1253]  mP[c*32+x]    partial weighted pair sum
#define WS_CAP  0
#define WS_NPOS 608
#define WS_SYP  627
#define WS_M    646

// Block-wide sum (256 threads = 4 waves). Result valid on tid==0 only.
__device__ __forceinline__ float block_sum(float v, int tid, float* red4) {
    #pragma unroll
    for (int off = 32; off > 0; off >>= 1) v += __shfl_down(v, off, 64);
    if ((tid & 63) == 0) red4[tid >> 6] = v;
    __syncthreads();
    float r = 0.0f;
    if (tid == 0) r = red4[0] + red4[1] + red4[2] + red4[3];
    __syncthreads();
    return r;
}

// K1: grid (32,19) x 256. Per-class partial cap counts; block x==0 also does
// the B-reductions (n_pos, sum_yp). Plain writes; kernel boundary publishes.
__global__ void __launch_bounds__(B_DIM)
rocstar_k1(const float* __restrict__ y_pred,
           const float* __restrict__ y_true,
           const float* __restrict__ epoch_true,
           float* __restrict__ ws) {
    const int c   = blockIdx.y;
    const int x   = blockIdx.x;
    const int tid = threadIdx.x;
    const int j   = x * B_DIM + tid;
    __shared__ float red4[4];

    const float cnt = (epoch_true[j * C_DIM + c] >= 0.5f) ? 1.0f : 0.0f;
    const float cs  = block_sum(cnt, tid, red4);
    if (tid == 0) ws[WS_CAP + c * XBLK + x] = cs;

    if (x == 0) {
        const float ypv = y_pred[tid * C_DIM + c];
        const float ytv = (y_true[tid * C_DIM + c] >= 0.5f) ? 1.0f : 0.0f;
        const float np  = block_sum(ytv, tid, red4);
        if (tid == 0) ws[WS_NPOS + c] = np;
        const float sy  = block_sum(ypv, tid, red4);
        if (tid == 0) ws[WS_SYP + c] = sy;
    }
}

// K2: grid (32,19) x 256. Double-compacted pair sums:
//  j-axis: only ~p*256 threads have w!=0 -> ballot-compact {a,s} into s_act.
//  i-axis: s=+1 (epoch neg) needs pm=1 rows only; s=-1 needs pm=0 rows only ->
//          compact yp into pos/neg lists, sentinel-padded so the relu kills pads.
// Inner loop: 3 VALU/element over ~max(np,nn) elements, one active wave.
__global__ void __launch_bounds__(B_DIM)
rocstar_k2(const float* __restrict__ y_pred,
           const float* __restrict__ y_true,
           const float* __restrict__ epoch_pred,
           const float* __restrict__ epoch_true,
           const float* __restrict__ gamma,
           const float* __restrict__ rand_pos,
           const float* __restrict__ rand_neg,
           float* __restrict__ ws) {
    const int c   = blockIdx.y;
    const int x   = blockIdx.x;
    const int tid = threadIdx.x;
    const int j   = x * B_DIM + tid;
    const int wv  = tid >> 6;
    const int ln  = tid & 63;

    __shared__ __align__(8) float s_pos[B_DIM];  // yp where pm=1, pad +1e30
    __shared__ __align__(8) float s_neg[B_DIM];  // yp where pm=0, pad -1e30
    __shared__ float2 s_act[B_DIM];              // {a, s} of active j's
    __shared__ int    s_pcnt[4], s_acnt[4];
    __shared__ float  red4[4];

    // ---- per-thread loads ----
    const float yp  = y_pred[tid * C_DIM + c];
    const bool  pmb = (y_true[tid * C_DIM + c] >= 0.5f);

    float cap = 0.0f;
    #pragma unroll
    for (int t = 0; t < XBLK; ++t) cap += ws[WS_CAP + c * XBLK + t];
    const float p = 1000.0f / fmaxf(cap, 1.0f);   // MAX_POS / cap_pos (f32, as ref)
    const float g = gamma[c];

    const float ep = epoch_pred[j * C_DIM + c];
    const bool  et = epoch_true[j * C_DIM + c] >= 0.5f;
    const float rp = rand_pos[j * C_DIM + c];
    const float rn = rand_neg[j * C_DIM + c];

    // faithful to the reference "bug": both masks use p from cap_pos
    const bool  act = (et ? rp : rn) < p;
    // et=0 (epoch neg, m2): d = (ep - yp) + g vs pm=1 rows -> s = +1
    // et=1 (epoch pos, m3): d = (yp - ep) + g vs pm=0 rows -> s = -1
    const float s = et ? -1.0f : 1.0f;
    const float a = fmaf(s, ep, g);               // s*ep + g

    // ---- ballots & per-wave counts ----
    const unsigned long long pmask = __ballot(pmb);
    const unsigned long long amask = __ballot(act);
    if (ln == 0) { s_pcnt[wv] = __popcll(pmask); s_acnt[wv] = __popcll(amask); }
    __syncthreads();

    int posBase = 0, actBase = 0, np = 0, total = 0;
    #pragma unroll
    for (int wk = 0; wk < 4; ++wk) {
        const int pc = s_pcnt[wk], ac = s_acnt[wk];
        np    += pc;
        total += ac;
        if (wk < wv) { posBase += pc; actBase += ac; }
    }
    const int negBase = (wv << 6) - posBase;      // 64*wv - pos_prefix
    const unsigned long long lt = (1ull << ln) - 1ull;
    const int prank = __popcll(pmask & lt);
    const int arank = __popcll(amask & lt);

    // ---- scatter compacted data ----
    if (pmb) s_pos[posBase + prank]       = yp;
    else     s_neg[negBase + (ln - prank)] = yp;
    if (act) s_act[actBase + arank] = make_float2(a, s);

    // ---- sentinel pads (relu kills them: s=+1 reads d=a-yp, s=-1 reads d=a+yp)
    const int nn   = B_DIM - np;
    const int mx   = (np > nn) ? np : nn;
    const int trip = (mx + 1) >> 1;
    const int lim  = trip << 1;                   // <= 256
    if (tid >= np && tid < lim) s_pos[tid] =  1.0e30f;
    if (tid >= nn && tid < lim) s_neg[tid] = -1.0e30f;
    __syncthreads();

    // ---- compacted inner loop (typically ~62 of 256 threads, ~68 f2 iters) ----
    float acc0 = 0.0f, acc1 = 0.0f;
    if (tid < total) {
        const float2 as  = s_act[tid];
        const float  ns  = -as.y;
        const float2* lst = (as.y > 0.0f) ? (const float2*)s_pos
                                          : (const float2*)s_neg;
        #pragma unroll 4
        for (int k = 0; k < trip; ++k) {
            const float2 v = lst[k];              // 2-address broadcast: free
            float d0 = fmaxf(fmaf(ns, v.x, as.x), 0.0f);
            acc0 = fmaf(d0, d0, acc0);
            float d1 = fmaxf(fmaf(ns, v.y, as.x), 0.0f);
            acc1 = fmaf(d1, d1, acc1);
        }
    }

    const float bs = block_sum(acc0 + acc1, tid, red4);
    if (tid == 0) ws[WS_M + c * XBLK + x] = bs;
}

// K3: one block. Thread c<19 folds its class's 32 partials + degenerate logic;
// single-wave shuffle reduce over classes.
__global__ void rocstar_k3(const float* __restrict__ ws,
                           float* __restrict__ out) {
    const int tid = threadIdx.x;
    float r = 0.0f;
    if (tid < C_DIM) {
        float m = 0.0f;
        #pragma unroll
        for (int t = 0; t < XBLK; ++t) m += ws[WS_M + tid * XBLK + t];
        float v = m / 1000.0f;                  // m2/MAX_POS + m3/MAX_NEG
        if (isnan(v)) v = 0.0f;
        const float npos = ws[WS_NPOS + tid];
        r = (npos == 0.0f || npos == (float)B_DIM)
                ? ws[WS_SYP + tid] * 1e-8f      // degenerate: sum(yp)*1e-8
                : v;
    }
    #pragma unroll
    for (int off = 16; off > 0; off >>= 1) r += __shfl_down(r, off, 64);
    if (tid == 0) out[0] = r / (float)C_DIM;    // mean over classes
}

extern "C" void kernel_launch(void* const* d_in, const int* in_sizes, int n_in,
                              void* d_out, int out_size, void* d_ws, size_t ws_size,
                              hipStream_t stream) {
    const float* y_pred     = (const float*)d_in[0];
    const float* y_true     = (const float*)d_in[1];
    const float* epoch_pred = (const float*)d_in[2];
    const float* epoch_true = (const float*)d_in[3];
    const float* gamma      = (const float*)d_in[4];
    const float* rand_pos   = (const float*)d_in[5];
    const float* rand_neg   = (const float*)d_in[6];
    float*       out        = (float*)d_out;
    float*       ws         = (float*)d_ws;

    const dim3 grid(XBLK, C_DIM);   // 32 x 19
    rocstar_k1<<<grid, B_DIM, 0, stream>>>(y_pred, y_true, epoch_true, ws);
    rocstar_k2<<<grid, B_DIM, 0, stream>>>(y_pred, y_true, epoch_pred, epoch_true,
                                           gamma, rand_pos, rand_neg, ws);
    rocstar_k3<<<1, 64, 0, stream>>>(ws, out);
}